// Round 12
// baseline (516.925 us; speedup 1.0000x reference)
//
#include <hip/hip_runtime.h>
#include <hip/hip_cooperative_groups.h>
#include <math.h>

namespace cg = cooperative_groups;

namespace {
constexpr int kL    = 262144;
constexpr int kC    = 256;
constexpr int kNH   = 8;
constexpr int kG    = 64;
constexpr int kFF   = 2048;
constexpr int kLPAD = 262144;
constexpr int kBS   = 4;
constexpr int kNW   = kLPAD / kG;   // 4096
constexpr int kS    = kNW / kBS;    // 1024
constexpr int kHD   = kC / kNH;     // 32

constexpr size_t MB        = 1024 * 1024;
constexpr size_t OFF_GIDX   = 0;         // int[LPAD]      1MB
constexpr size_t OFF_WINNER = 1 * MB;    // int[L]         1MB
constexpr size_t OFF_WLIST  = 2 * MB;    // int[L]         1MB
constexpr size_t OFF_CNT    = 3 * MB;    // int[1]
constexpr size_t OFF_X0     = 4 * MB;    // f32[4096*256]  4MB
constexpr size_t OFF_BASE   = 8 * MB;    // f32[4096*256]  4MB
constexpr size_t OFF_ATTN   = 12 * MB;   // bf16[4096*256] 2MB
constexpr size_t OFF_QH     = 16 * MB;   // bf16 2MB
constexpr size_t OFF_KH     = 18 * MB;   // 2MB
constexpr size_t OFF_VH     = 20 * MB;   // 2MB
constexpr size_t OFF_X1     = 24 * MB;   // f32[4096*256]  4MB
constexpr size_t OFF_FF1    = 32 * MB;   // bf16[4096*2048] 16MB
constexpr size_t OFF_WINB   = 64 * MB;                 // bf16[768*256]  384KB
constexpr size_t OFF_WOUTB  = OFF_WINB  + 512 * 1024;  // bf16[256*256]  128KB
constexpr size_t OFF_W1B    = OFF_WOUTB + 256 * 1024;  // bf16[2048*256] 1MB
constexpr size_t OFF_W2B    = OFF_W1B   + 1536 * 1024; // bf16[256*2048] 1MB
constexpr size_t OFF_WP1B   = OFF_W2B   + 1536 * 1024; // bf16[256*256]  128KB
constexpr size_t OFF_WP2B   = OFF_WP1B  + 256 * 1024;  // bf16[256*256]  128KB

typedef __attribute__((ext_vector_type(8))) short bf16x8;
typedef __attribute__((ext_vector_type(4))) float f32x4;

__device__ inline unsigned short f2bf(float f) {
  union { float f; unsigned int u; } x; x.f = f;
  unsigned int r = x.u + 0x7fff + ((x.u >> 16) & 1);   // RNE
  return (unsigned short)(r >> 16);
}
} // namespace

// ---------------------------------------------------------------- winner init (int4 per thread)
__global__ __launch_bounds__(256) void k_initw(int* __restrict__ winner,
                                               int* __restrict__ cnt) {
  int i = blockIdx.x * 256 + threadIdx.x;
  ((int4*)winner)[i] = make_int4(-1, -1, -1, -1);
  if (i == 0) cnt[0] = 0;
}

// ---------------------------------------------------------------- winner (4 per thread)
__global__ __launch_bounds__(256) void k_winner(const int* __restrict__ x_idx,
                                                int* __restrict__ winner) {
  int i0 = (blockIdx.x * 256 + threadIdx.x) * 4;
  int4 xi = *(const int4*)&x_idx[i0];
  atomicMax(&winner[xi.x], i0);
  atomicMax(&winner[xi.y], i0 + 1);
  atomicMax(&winner[xi.z], i0 + 2);
  atomicMax(&winner[xi.w], i0 + 3);
}

// ---------------------------------------------------------------- merged: compact (blk<256, 4/thread) + weight casts
__global__ __launch_bounds__(256) void k_fc(const int* __restrict__ x_idx,
                                            const int* __restrict__ winner,
                                            int* __restrict__ wlist,
                                            int* __restrict__ cnt,
                                            const float* __restrict__ in_proj_w,
                                            const float* __restrict__ out_proj_w,
                                            const float* __restrict__ lin1_w,
                                            const float* __restrict__ lin2_w,
                                            const float* __restrict__ proj_w,
                                            unsigned short* __restrict__ WINB,
                                            unsigned short* __restrict__ WOUTB,
                                            unsigned short* __restrict__ W1B,
                                            unsigned short* __restrict__ W2B,
                                            unsigned short* __restrict__ WP1,
                                            unsigned short* __restrict__ WP2) {
  int blk = blockIdx.x, t = threadIdx.x;
  if (blk < 256) {                      // compact, 4 elements/thread
    int i0 = (blk * 256 + t) * 4;
    int4 xi = *(const int4*)&x_idx[i0];
    #pragma unroll
    for (int j = 0; j < 4; ++j) {
      int i = i0 + j;
      int xv = (j == 0) ? xi.x : (j == 1) ? xi.y : (j == 2) ? xi.z : xi.w;
      if (winner[xv] == i) {
        int p = atomicAdd(cnt, 1);
        wlist[p] = i;
      }
    }
    return;
  }
  int b2 = blk - 256;                   // weight casts
  const float* src = nullptr; unsigned short* dst = nullptr; int i = 0;
  if (b2 < 192)       { src = in_proj_w;  dst = WINB;  i = b2 * 256 + t; }
  else if (b2 < 256)  { src = out_proj_w; dst = WOUTB; i = (b2 - 192) * 256 + t; }
  else if (b2 < 768)  { src = lin1_w;     dst = W1B;   i = (b2 - 256) * 256 + t; }
  else if (b2 < 1280) { src = lin2_w;     dst = W2B;   i = (b2 - 768) * 256 + t; }
  else {
    int c = b2 - 1280;
    WP1[c * kC + t] = f2bf(proj_w[(size_t)c * (2 * kC) + t]);
    WP2[c * kC + t] = f2bf(proj_w[(size_t)c * (2 * kC) + kC + t]);
    return;
  }
  float4 v = ((const float4*)src)[i];
  ushort4 b;
  b.x = f2bf(v.x); b.y = f2bf(v.y); b.z = f2bf(v.z); b.w = f2bf(v.w);
  ((ushort4*)dst)[i] = b;
}

// ---------------------------------------------------------------- merged: pool (blk<4096, wave-per-row) + copy (8 rows/blk)
__global__ __launch_bounds__(256) void k_pc(const float* __restrict__ feats,
                                            const int* __restrict__ x_idx,
                                            const int* __restrict__ flat2win,
                                            const int* __restrict__ winner,
                                            int* __restrict__ gidx,
                                            float* __restrict__ x0,
                                            float* __restrict__ out) {
  int blk = blockIdx.x, t = threadIdx.x;
  int w = t >> 6, lane = t & 63;
  if (blk < kNW) {                       // pool: wave w handles rows w*16..w*16+15
    __shared__ int rows[kG];
    __shared__ __align__(16) float mred[4][kC];
    if (t < kG) {
      int g = x_idx[flat2win[blk * kG + t]];
      rows[t] = g;
      gidx[blk * kG + t] = g;
    }
    __syncthreads();
    float4 mx = make_float4(-INFINITY, -INFINITY, -INFINITY, -INFINITY);
    #pragma unroll
    for (int i = 0; i < 16; ++i) {
      int r = rows[w * 16 + i];
      float4 v = *(const float4*)&feats[(size_t)r * kC + lane * 4];
      mx.x = fmaxf(mx.x, v.x); mx.y = fmaxf(mx.y, v.y);
      mx.z = fmaxf(mx.z, v.z); mx.w = fmaxf(mx.w, v.w);
    }
    *(float4*)&mred[w][lane * 4] = mx;
    __syncthreads();
    x0[blk * kC + t] = fmaxf(fmaxf(mred[0][t], mred[1][t]),
                             fmaxf(mred[2][t], mred[3][t]));
    return;
  }
  // copy rows not overwritten by fuse scatter: 8 rows per block (2 per wave)
  int cb = blk - kNW;                    // 0..32767  (kL/8 blocks)
  #pragma unroll
  for (int i = 0; i < 2; ++i) {
    int row = cb * 8 + w * 2 + i;
    if (winner[row] < 0) {
      *(float4*)&out[(size_t)row * kC + lane * 4] =
          *(const float4*)&feats[(size_t)row * kC + lane * 4];
    }
  }
}

// ================================================================ transformer device bodies
__device__ __forceinline__ void qkv_body(int sec, int my, char* smem,
                                         const float* __restrict__ A,
                                         const unsigned short* __restrict__ Wb,
                                         const float* __restrict__ bias,
                                         unsigned short* __restrict__ Qh,
                                         unsigned short* __restrict__ Kh,
                                         unsigned short* __restrict__ Vh) {
  const float scale = 0.17677669529663687f;   // 1/sqrt(32)
  const int m0 = my * 64;
  const int t = threadIdx.x;
  const int lane = t & 63, w = t >> 6;
  const int c0 = w * 64;
  const int kb = lane >> 4, lr = lane & 15;
  char* As = smem;                             // 32KB swizzled

  f32x4 acc[4][4] = {};
  #pragma unroll
  for (int i = 0; i < 16; ++i) {
    int row = i * 4 + w;
    float4 f4 = *(const float4*)&A[(size_t)(m0 + row) * kC + lane * 4];
    ushort4 b4;
    b4.x = f2bf(f4.x); b4.y = f2bf(f4.y); b4.z = f2bf(f4.z); b4.w = f2bf(f4.w);
    unsigned int off = (((unsigned)row * 512u) + (unsigned)lane * 8u) ^ (((unsigned)row & 7u) << 4);
    *(ushort4*)(As + off) = b4;
  }
  __syncthreads();

  #pragma unroll
  for (int ks = 0; ks < 8; ++ks) {
    const int k0 = ks * 32;
    bf16x8 a[4], b[4];
    #pragma unroll
    for (int rt = 0; rt < 4; ++rt) {
      int row = rt * 16 + lr;
      unsigned int off = (((unsigned)row * 512u) + (unsigned)(k0 + kb * 8) * 2u) ^
                         (((unsigned)row & 7u) << 4);
      a[rt] = *(const bf16x8*)(As + off);
    }
    #pragma unroll
    for (int ct = 0; ct < 4; ++ct) {
      int c = sec * kC + c0 + ct * 16 + lr;
      b[ct] = *(const bf16x8*)&Wb[(size_t)c * kC + k0 + kb * 8];
    }
    #pragma unroll
    for (int rt = 0; rt < 4; ++rt)
      #pragma unroll
      for (int ct = 0; ct < 4; ++ct)
        acc[rt][ct] = __builtin_amdgcn_mfma_f32_16x16x32_bf16(a[rt], b[ct], acc[rt][ct], 0, 0, 0);
  }

  unsigned short* dstbuf = (sec == 0) ? Qh : (sec == 1) ? Kh : Vh;
  #pragma unroll
  for (int rt = 0; rt < 4; ++rt) {
    #pragma unroll
    for (int r = 0; r < 4; ++r) {
      int row = m0 + rt * 16 + kb * 4 + r;
      int bb = row >> 10, s = row & 1023;
      #pragma unroll
      for (int ct = 0; ct < 4; ++ct) {
        int c = c0 + ct * 16 + lr;
        float v = acc[rt][ct][r] + bias[sec * kC + c];
        if (sec == 0) v *= scale;
        int h = c >> 5, d = c & 31;
        dstbuf[(((size_t)(bb * kNH + h) * kS) + s) * kHD + d] = f2bf(v);
      }
    }
  }
}

__device__ __forceinline__ void attn_body(int bxq, int bh, char* smem,
                                          const unsigned short* __restrict__ Qh,
                                          const unsigned short* __restrict__ Kh,
                                          const unsigned short* __restrict__ Vh,
                                          unsigned short* __restrict__ attn_out) {
  const int q0 = bxq * 64;
  const int b = bh >> 3, h = bh & 7;
  const int t = threadIdx.x;
  const int lane = t & 63, w = t >> 6;
  const int kb = lane >> 4, lr = lane & 15;

  unsigned short (*Ks)[40]       = (unsigned short (*)[40])(smem);           // 10240B
  unsigned short (*VTs)[136]     = (unsigned short (*)[136])(smem + 10240);  // 8704B
  unsigned short (*Ps)[16][136]  = (unsigned short (*)[16][136])(smem + 18944); // 17408B

  bf16x8 aq = *(const bf16x8*)(Qh + (((size_t)bh * kS) + q0 + w * 16 + lr) * kHD + kb * 8);

  const unsigned short* kbase = Kh + (size_t)bh * kS * kHD;
  const unsigned short* vbase = Vh + (size_t)bh * kS * kHD;

  float m[4], l[4];
  f32x4 O[2] = {};
  #pragma unroll
  for (int r = 0; r < 4; ++r) { m[r] = -INFINITY; l[r] = 0.f; }

  for (int kt = 0; kt < kS / 128; ++kt) {
    {
      int key = t >> 1, d0 = (t & 1) * 16;
      size_t srow = ((size_t)(kt * 128 + key)) * kHD + d0;
      bf16x8 kv0 = *(const bf16x8*)(kbase + srow);
      bf16x8 kv1 = *(const bf16x8*)(kbase + srow + 8);
      *(bf16x8*)&Ks[key][d0] = kv0;
      *(bf16x8*)&Ks[key][d0 + 8] = kv1;
      bf16x8 vv0 = *(const bf16x8*)(vbase + srow);
      bf16x8 vv1 = *(const bf16x8*)(vbase + srow + 8);
      #pragma unroll
      for (int i = 0; i < 8; ++i) {
        VTs[d0 + i][key] = (unsigned short)vv0[i];
        VTs[d0 + 8 + i][key] = (unsigned short)vv1[i];
      }
    }
    __syncthreads();

    f32x4 S[8] = {};
    #pragma unroll
    for (int ct = 0; ct < 8; ++ct) {
      bf16x8 bk = *(const bf16x8*)&Ks[ct * 16 + lr][kb * 8];
      S[ct] = __builtin_amdgcn_mfma_f32_16x16x32_bf16(aq, bk, S[ct], 0, 0, 0);
    }

    float alpha[4];
    #pragma unroll
    for (int r = 0; r < 4; ++r) {
      float tmax = -INFINITY;
      #pragma unroll
      for (int ct = 0; ct < 8; ++ct) tmax = fmaxf(tmax, S[ct][r]);
      #pragma unroll
      for (int off = 8; off; off >>= 1) tmax = fmaxf(tmax, __shfl_xor(tmax, off, 16));
      float newm = fmaxf(m[r], tmax);
      alpha[r] = __expf(m[r] - newm);
      float ps = 0.f;
      #pragma unroll
      for (int ct = 0; ct < 8; ++ct) {
        float p = __expf(S[ct][r] - newm);
        ps += p;
        Ps[w][kb * 4 + r][ct * 16 + lr] = f2bf(p);
      }
      #pragma unroll
      for (int off = 8; off; off >>= 1) ps += __shfl_xor(ps, off, 16);
      l[r] = l[r] * alpha[r] + ps;
      m[r] = newm;
    }
    #pragma unroll
    for (int r = 0; r < 4; ++r) { O[0][r] *= alpha[r]; O[1][r] *= alpha[r]; }

    #pragma unroll
    for (int ks = 0; ks < 4; ++ks) {
      bf16x8 ap = *(const bf16x8*)&Ps[w][lr][ks * 32 + kb * 8];
      #pragma unroll
      for (int ct = 0; ct < 2; ++ct) {
        bf16x8 bv = *(const bf16x8*)&VTs[ct * 16 + lr][ks * 32 + kb * 8];
        O[ct] = __builtin_amdgcn_mfma_f32_16x16x32_bf16(ap, bv, O[ct], 0, 0, 0);
      }
    }
    __syncthreads();
  }

  #pragma unroll
  for (int ct = 0; ct < 2; ++ct) {
    #pragma unroll
    for (int r = 0; r < 4; ++r) {
      size_t row = (size_t)b * kS + q0 + w * 16 + kb * 4 + r;
      attn_out[row * kC + h * kHD + ct * 16 + lr] = f2bf(O[ct][r] / l[r]);
    }
  }
}

template <bool DO_BASE>
__device__ __forceinline__ void gemm_ln_body(int bx, char* smem,
                                             const unsigned short* __restrict__ A,
                                             int K,
                                             const unsigned short* __restrict__ Wb,
                                             const float* __restrict__ bias,
                                             const float* __restrict__ R,
                                             const float* __restrict__ g,
                                             const float* __restrict__ bb,
                                             float* __restrict__ Out,
                                             const unsigned short* __restrict__ WbB,
                                             const float* __restrict__ biasB) {
  const int m0 = bx * 16;
  const int t = threadIdx.x;
  const int lane = t & 63, w = t >> 6;
  const int c0 = w * 64;
  const int kb = lane >> 4, lr = lane & 15;

  char* As = smem;                         // 8KB
  char* Xs = smem + 8192;                  // 8KB
  float (*red)[16][4] = (float (*)[16][4])(smem + 16384);   // 512B

  f32x4 acc[4] = {};
  for (int kc = 0; kc < K; kc += 256) {
    #pragma unroll
    for (int i = 0; i < 2; ++i) {
      int idx = i * 256 + t;
      int row = idx >> 5, seg = idx & 31;
      bf16x8 v = *(const bf16x8*)&A[(size_t)(m0 + row) * K + kc + seg * 8];
      unsigned int off = (((unsigned)row * 512u) + (unsigned)seg * 16u) ^ (((unsigned)row & 7u) << 4);
      *(bf16x8*)(As + off) = v;
    }
    __syncthreads();

    #pragma unroll
    for (int ks = 0; ks < 8; ++ks) {
      const int k0 = ks * 32;
      unsigned int aoff = (((unsigned)lr * 512u) + (unsigned)(k0 + kb * 8) * 2u) ^
                          (((unsigned)lr & 7u) << 4);
      bf16x8 a = *(const bf16x8*)(As + aoff);
      #pragma unroll
      for (int ct = 0; ct < 4; ++ct) {
        bf16x8 b = *(const bf16x8*)&Wb[(size_t)(c0 + ct * 16 + lr) * K + kc + k0 + kb * 8];
        acc[ct] = __builtin_amdgcn_mfma_f32_16x16x32_bf16(a, b, acc[ct], 0, 0, 0);
      }
    }
    __syncthreads();
  }

  float v[4][4];
  float s[4], sq[4];
  #pragma unroll
  for (int r = 0; r < 4; ++r) { s[r] = 0.f; sq[r] = 0.f; }
  #pragma unroll
  for (int r = 0; r < 4; ++r) {
    int row = m0 + kb * 4 + r;
    #pragma unroll
    for (int ct = 0; ct < 4; ++ct) {
      int c = c0 + ct * 16 + lr;
      float x = acc[ct][r] + bias[c] + R[(size_t)row * kC + c];
      v[r][ct] = x;
      s[r] += x;
      sq[r] += x * x;
    }
  }
  #pragma unroll
  for (int r = 0; r < 4; ++r) {
    #pragma unroll
    for (int off = 8; off; off >>= 1) {
      s[r]  += __shfl_xor(s[r], off, 16);
      sq[r] += __shfl_xor(sq[r], off, 16);
    }
    if (lr == 0) { red[0][kb * 4 + r][w] = s[r]; red[1][kb * 4 + r][w] = sq[r]; }
  }
  __syncthreads();

  #pragma unroll
  for (int r = 0; r < 4; ++r) {
    int lrow = kb * 4 + r;
    float su = red[0][lrow][0] + red[0][lrow][1] + red[0][lrow][2] + red[0][lrow][3];
    float sg = red[1][lrow][0] + red[1][lrow][1] + red[1][lrow][2] + red[1][lrow][3];
    float mu = su * (1.0f / kC);
    float var = sg * (1.0f / kC) - mu * mu;
    float rs = rsqrtf(var + 1e-5f);
    #pragma unroll
    for (int ct = 0; ct < 4; ++ct) {
      int c = c0 + ct * 16 + lr;
      float yv = (v[r][ct] - mu) * rs * g[c] + bb[c];
      if (!DO_BASE) {
        Out[(size_t)(m0 + lrow) * kC + c] = yv;
      } else {
        unsigned int off = (((unsigned)lrow * 512u) + (unsigned)c * 2u) ^ (((unsigned)lrow & 7u) << 4);
        *(unsigned short*)(Xs + off) = f2bf(yv);
      }
    }
  }

  if (DO_BASE) {
    __syncthreads();
    f32x4 acc2[4] = {};
    #pragma unroll
    for (int ks = 0; ks < 8; ++ks) {
      const int k0 = ks * 32;
      unsigned int aoff = (((unsigned)lr * 512u) + (unsigned)(k0 + kb * 8) * 2u) ^
                          (((unsigned)lr & 7u) << 4);
      bf16x8 a = *(const bf16x8*)(Xs + aoff);
      #pragma unroll
      for (int ct = 0; ct < 4; ++ct) {
        bf16x8 b = *(const bf16x8*)&WbB[(size_t)(c0 + ct * 16 + lr) * kC + k0 + kb * 8];
        acc2[ct] = __builtin_amdgcn_mfma_f32_16x16x32_bf16(a, b, acc2[ct], 0, 0, 0);
      }
    }
    #pragma unroll
    for (int r = 0; r < 4; ++r) {
      int row = m0 + kb * 4 + r;
      #pragma unroll
      for (int ct = 0; ct < 4; ++ct) {
        int c = c0 + ct * 16 + lr;
        Out[(size_t)row * kC + c] = acc2[ct][r] + biasB[c];
      }
    }
  }
}

__device__ __forceinline__ void ff1_body(int nx, int my, char* smem,
                                         const float* __restrict__ A,
                                         const unsigned short* __restrict__ Wb,
                                         const float* __restrict__ bias,
                                         unsigned short* __restrict__ Cc) {
  const int m0 = my * 64;
  const int nb = nx * 256;
  const int t = threadIdx.x;
  const int lane = t & 63, w = t >> 6;
  const int c0 = nb + w * 64;
  const int kb = lane >> 4, lr = lane & 15;
  char* As = smem;                        // 32KB

  f32x4 acc[4][4] = {};
  #pragma unroll
  for (int i = 0; i < 16; ++i) {
    int row = i * 4 + w;
    float4 f4 = *(const float4*)&A[(size_t)(m0 + row) * kC + lane * 4];
    ushort4 b4;
    b4.x = f2bf(f4.x); b4.y = f2bf(f4.y); b4.z = f2bf(f4.z); b4.w = f2bf(f4.w);
    unsigned int off = (((unsigned)row * 512u) + (unsigned)lane * 8u) ^ (((unsigned)row & 7u) << 4);
    *(ushort4*)(As + off) = b4;
  }
  __syncthreads();

  #pragma unroll
  for (int ks = 0; ks < 8; ++ks) {
    const int k0 = ks * 32;
    bf16x8 a[4], b[4];
    #pragma unroll
    for (int rt = 0; rt < 4; ++rt) {
      int row = rt * 16 + lr;
      unsigned int off = (((unsigned)row * 512u) + (unsigned)(k0 + kb * 8) * 2u) ^
                         (((unsigned)row & 7u) << 4);
      a[rt] = *(const bf16x8*)(As + off);
    }
    #pragma unroll
    for (int ct = 0; ct < 4; ++ct) {
      int c = c0 + ct * 16 + lr;
      b[ct] = *(const bf16x8*)&Wb[(size_t)c * kC + k0 + kb * 8];
    }
    #pragma unroll
    for (int rt = 0; rt < 4; ++rt)
      #pragma unroll
      for (int ct = 0; ct < 4; ++ct)
        acc[rt][ct] = __builtin_amdgcn_mfma_f32_16x16x32_bf16(a[rt], b[ct], acc[rt][ct], 0, 0, 0);
  }

  #pragma unroll
  for (int rt = 0; rt < 4; ++rt) {
    #pragma unroll
    for (int r = 0; r < 4; ++r) {
      int row = m0 + rt * 16 + kb * 4 + r;
      #pragma unroll
      for (int ct = 0; ct < 4; ++ct) {
        int c = c0 + ct * 16 + lr;
        float vv = fmaxf(acc[rt][ct][r] + bias[c], 0.f);
        Cc[(size_t)row * kFF + c] = f2bf(vv);
      }
    }
  }
}

// ---------------------------------------------------------------- cooperative mid-section
struct FormerArgs {
  const float* x0;
  const unsigned short* WINB; const float* in_proj_b;
  unsigned short* Qh; unsigned short* Kh; unsigned short* Vh;
  unsigned short* attnb;
  const unsigned short* WOUTB; const float* out_proj_b;
  const float* ln1_g; const float* ln1_b; float* x1;
  const unsigned short* W1B; const float* lin1_b; unsigned short* ff1b;
  const unsigned short* W2B; const float* lin2_b;
  const float* ln2_g; const float* ln2_b;
  const unsigned short* WP1B; const float* proj_b; float* basep;
};

__global__ __launch_bounds__(256, 2) void k_former(FormerArgs a) {
  __shared__ __align__(16) char smem[36864];
  cg::grid_group grid = cg::this_grid();
  const int gsz = gridDim.x;

  // phase 1: qkv (192 units: sec 0..2 x my 0..63)
  for (int u = blockIdx.x; u < 192; u += gsz) {
    qkv_body(u % 3, u / 3, smem, a.x0, a.WINB, a.in_proj_b, a.Qh, a.Kh, a.Vh);
    __syncthreads();
  }
  grid.sync();
  // phase 2: attn (512 units: bxq 0..15 x bh 0..31)
  for (int u = blockIdx.x; u < 512; u += gsz) {
    attn_body(u % 16, u / 16, smem, a.Qh, a.Kh, a.Vh, a.attnb);
    __syncthreads();
  }
  grid.sync();
  // phase 3: out_proj + residual(x0) + LN1 -> x1 (256 units)
  for (int u = blockIdx.x; u < 256; u += gsz) {
    gemm_ln_body<false>(u, smem, a.attnb, kC, a.WOUTB, a.out_proj_b,
                        a.x0, a.ln1_g, a.ln1_b, a.x1, nullptr, nullptr);
    __syncthreads();
  }
  grid.sync();
  // phase 4: ff1 (512 units: nx 0..7 x my 0..63)
  for (int u = blockIdx.x; u < 512; u += gsz) {
    ff1_body(u % 8, u / 8, smem, a.x1, a.W1B, a.lin1_b, a.ff1b);
    __syncthreads();
  }
  grid.sync();
  // phase 5: lin2 + residual(x1) + LN2 -> chained base (256 units)
  for (int u = blockIdx.x; u < 256; u += gsz) {
    gemm_ln_body<true>(u, smem, a.ff1b, kFF, a.W2B, a.lin2_b,
                       a.x1, a.ln2_g, a.ln2_b, a.basep, a.WP1B, a.proj_b);
    __syncthreads();
  }
}

// ---------------------------------------------------------------- standalone fallback wrappers (R9 path)
__global__ __launch_bounds__(256) void k_qkv_sa(FormerArgs a) {
  __shared__ __align__(16) char smem[32768];
  qkv_body(blockIdx.x, blockIdx.y, smem, a.x0, a.WINB, a.in_proj_b, a.Qh, a.Kh, a.Vh);
}
__global__ __launch_bounds__(256) void k_attn_sa(FormerArgs a) {
  __shared__ __align__(16) char smem[36352];
  attn_body(blockIdx.x, blockIdx.y, smem, a.Qh, a.Kh, a.Vh, a.attnb);
}
__global__ __launch_bounds__(256) void k_ln1_sa(FormerArgs a) {
  __shared__ __align__(16) char smem[16896];
  gemm_ln_body<false>(blockIdx.x, smem, a.attnb, kC, a.WOUTB, a.out_proj_b,
                      a.x0, a.ln1_g, a.ln1_b, a.x1, nullptr, nullptr);
}
__global__ __launch_bounds__(256) void k_ff1_sa(FormerArgs a) {
  __shared__ __align__(16) char smem[32768];
  ff1_body(blockIdx.x, blockIdx.y, smem, a.x1, a.W1B, a.lin1_b, a.ff1b);
}
__global__ __launch_bounds__(256) void k_ln2_sa(FormerArgs a) {
  __shared__ __align__(16) char smem[16896];
  gemm_ln_body<true>(blockIdx.x, smem, a.ff1b, kFF, a.W2B, a.lin2_b,
                     a.x1, a.ln2_g, a.ln2_b, a.basep, a.WP1B, a.proj_b);
}

// ---------------------------------------------------------------- fuse: bf16 MFMA GEMM (gathered A) + scatter
__global__ __launch_bounds__(256) void k_fuse(const float* __restrict__ feats,
                                              const int* __restrict__ gidx,
                                              const int* __restrict__ wlist,
                                              const int* __restrict__ cnt,
                                              const int* __restrict__ win2flat,
                                              const int* __restrict__ x_idx,
                                              const float* __restrict__ base,
                                              const unsigned short* __restrict__ W2B,
                                              float* __restrict__ out) {
  const int count = cnt[0];
  const int r0 = blockIdx.x * 64;
  if (r0 >= count) return;
  const int nr = min(64, count - r0);
  const int t = threadIdx.x;
  const int lane = t & 63, w = t >> 6;

  __shared__ __align__(16) unsigned short As[64 * 256];
  __shared__ int dstrow[64], wwin[64], srcrow[64];

  if (t < 64) {
    int rr = min(r0 + t, count - 1);
    int i = wlist[rr];
    int j = win2flat[i];
    srcrow[t] = gidx[j];
    wwin[t] = j >> 6;
    dstrow[t] = x_idx[i];
  }
  __syncthreads();

  for (int i = 0; i < 16; ++i) {
    int row = i * 4 + w;
    float4 f4 = *(const float4*)&feats[(size_t)srcrow[row] * kC + lane * 4];
    ushort4 b4;
    b4.x = f2bf(f4.x); b4.y = f2bf(f4.y); b4.z = f2bf(f4.z); b4.w = f2bf(f4.w);
    unsigned int off = (((unsigned)row * 512u) + (unsigned)lane * 8u) ^ (((unsigned)row & 7u) << 4);
    *(ushort4*)((char*)As + off) = b4;
  }
  __syncthreads();

  const int c0 = w * 64;
  const int kb = lane >> 4;
  const int lr = lane & 15;
  f32x4 acc[4][4] = {};
  for (int ks = 0; ks < 8; ++ks) {
    const int k0 = ks * 32;
    bf16x8 a[4], b[4];
    #pragma unroll
    for (int rt = 0; rt < 4; ++rt) {
      int row = rt * 16 + lr;
      unsigned int off = (((unsigned)row * 512u) + (unsigned)(k0 + kb * 8) * 2u) ^
                         (((unsigned)row & 7u) << 4);
      a[rt] = *(const bf16x8*)((const char*)As + off);
    }
    #pragma unroll
    for (int ct = 0; ct < 4; ++ct) {
      int c = c0 + ct * 16 + lr;
      b[ct] = *(const bf16x8*)&W2B[(size_t)c * kC + k0 + kb * 8];
    }
    #pragma unroll
    for (int rt = 0; rt < 4; ++rt)
      #pragma unroll
      for (int ct = 0; ct < 4; ++ct)
        acc[rt][ct] = __builtin_amdgcn_mfma_f32_16x16x32_bf16(a[rt], b[ct], acc[rt][ct], 0, 0, 0);
  }

  #pragma unroll
  for (int rt = 0; rt < 4; ++rt) {
    #pragma unroll
    for (int r = 0; r < 4; ++r) {
      int row = rt * 16 + kb * 4 + r;
      if (row < nr) {
        size_t orow = (size_t)dstrow[row] * kC;
        size_t brow = (size_t)wwin[row] * kC;
        #pragma unroll
        for (int ct = 0; ct < 4; ++ct) {
          int c = c0 + ct * 16 + lr;
          out[orow + c] = acc[rt][ct][r] + base[brow + c];
        }
      }
    }
  }
}

// ---------------------------------------------------------------- launch
extern "C" void kernel_launch(void* const* d_in, const int* in_sizes, int n_in,
                              void* d_out, int out_size, void* d_ws, size_t ws_size,
                              hipStream_t stream) {
  const float* feats      = (const float*)d_in[0];
  const int*   x_idx      = (const int*)d_in[1];
  const int*   flat2win   = (const int*)d_in[2];
  const int*   win2flat   = (const int*)d_in[3];
  const float* in_proj_w  = (const float*)d_in[4];
  const float* in_proj_b  = (const float*)d_in[5];
  const float* out_proj_w = (const float*)d_in[6];
  const float* out_proj_b = (const float*)d_in[7];
  const float* lin1_w     = (const float*)d_in[8];
  const float* lin1_b     = (const float*)d_in[9];
  const float* lin2_w     = (const float*)d_in[10];
  const float* lin2_b     = (const float*)d_in[11];
  const float* ln1_g      = (const float*)d_in[12];
  const float* ln1_b      = (const float*)d_in[13];
  const float* ln2_g      = (const float*)d_in[14];
  const float* ln2_b      = (const float*)d_in[15];
  const float* proj_w     = (const float*)d_in[16];
  const float* proj_b     = (const float*)d_in[17];

  char* ws = (char*)d_ws;
  int*   gidx   = (int*)(ws + OFF_GIDX);
  int*   winner = (int*)(ws + OFF_WINNER);
  int*   wlist  = (int*)(ws + OFF_WLIST);
  int*   cnt    = (int*)(ws + OFF_CNT);
  float* x0     = (float*)(ws + OFF_X0);
  float* basep  = (float*)(ws + OFF_BASE);
  float* x1     = (float*)(ws + OFF_X1);
  unsigned short* attnb = (unsigned short*)(ws + OFF_ATTN);
  unsigned short* Qh    = (unsigned short*)(ws + OFF_QH);
  unsigned short* Kh    = (unsigned short*)(ws + OFF_KH);
  unsigned short* Vh    = (unsigned short*)(ws + OFF_VH);
  unsigned short* ff1b  = (unsigned short*)(ws + OFF_FF1);
  unsigned short* WINB  = (unsigned short*)(ws + OFF_WINB);
  unsigned short* WOUTB = (unsigned short*)(ws + OFF_WOUTB);
  unsigned short* W1B   = (unsigned short*)(ws + OFF_W1B);
  unsigned short* W2B   = (unsigned short*)(ws + OFF_W2B);
  unsigned short* WP1B  = (unsigned short*)(ws + OFF_WP1B);
  unsigned short* WP2B  = (unsigned short*)(ws + OFF_WP2B);
  float* out    = (float*)d_out;

  k_initw<<<kL / 1024, 256, 0, stream>>>(winner, cnt);
  k_winner<<<kL / 1024, 256, 0, stream>>>(x_idx, winner);
  k_fc<<<256 + 1536, 256, 0, stream>>>(x_idx, winner, wlist, cnt,
                                       in_proj_w, out_proj_w, lin1_w, lin2_w, proj_w,
                                       WINB, WOUTB, W1B, W2B, WP1B, WP2B);
  k_pc<<<kNW + kL / 8, 256, 0, stream>>>(feats, x_idx, flat2win, winner, gidx, x0, out);

  FormerArgs fa;
  fa.x0 = x0; fa.WINB = WINB; fa.in_proj_b = in_proj_b;
  fa.Qh = Qh; fa.Kh = Kh; fa.Vh = Vh;
  fa.attnb = attnb;
  fa.WOUTB = WOUTB; fa.out_proj_b = out_proj_b;
  fa.ln1_g = ln1_g; fa.ln1_b = ln1_b; fa.x1 = x1;
  fa.W1B = W1B; fa.lin1_b = lin1_b; fa.ff1b = ff1b;
  fa.W2B = W2B; fa.lin2_b = lin2_b;
  fa.ln2_g = ln2_g; fa.ln2_b = ln2_b;
  fa.WP1B = WP1B; fa.proj_b = proj_b; fa.basep = basep;

  // decide coop path via capture-safe queries (deterministic per system)
  bool done = false;
  int dev = 0;
  (void)hipGetDevice(&dev);
  int coopAttr = 0;
  (void)hipDeviceGetAttribute(&coopAttr, hipDeviceAttributeCooperativeLaunch, dev);
  if (coopAttr) {
    int maxB = 0;
    hipError_t oe = hipOccupancyMaxActiveBlocksPerMultiprocessor(
        &maxB, (const void*)k_former, 256, 0);
    int ncu = 0;
    (void)hipDeviceGetAttribute(&ncu, hipDeviceAttributeMultiprocessorCount, dev);
    if (oe == hipSuccess && maxB >= 1 && ncu >= 1) {
      int grid = maxB * ncu;
      if (grid > 512) grid = 512;
      void* kargs[] = { (void*)&fa };
      hipError_t le = hipLaunchCooperativeKernel((void*)k_former, dim3(grid), dim3(256),
                                                 kargs, 0, stream);
      done = (le == hipSuccess);
    }
  }
  if (!done) {   // fallback: R9-equivalent separate kernels
    k_qkv_sa<<<dim3(3, kNW / 64), 256, 0, stream>>>(fa);
    k_attn_sa<<<dim3(kS / 64, kBS * kNH), 256, 0, stream>>>(fa);
    k_ln1_sa<<<kNW / 16, 256, 0, stream>>>(fa);
    k_ff1_sa<<<dim3(kFF / 256, kNW / 64), 256, 0, stream>>>(fa);
    k_ln2_sa<<<kNW / 16, 256, 0, stream>>>(fa);
  }

  k_fuse<<<kL / 64, 256, 0, stream>>>(feats, gidx, wlist, cnt, win2flat, x_idx,
                                      basep, WP2B, out);
}

// Round 13
// 383.815 us; speedup vs baseline: 1.3468x; 1.3468x over previous
//
#include <hip/hip_runtime.h>
#include <math.h>

namespace {
constexpr int kL    = 262144;
constexpr int kC    = 256;
constexpr int kNH   = 8;
constexpr int kG    = 64;
constexpr int kFF   = 2048;
constexpr int kLPAD = 262144;
constexpr int kBS   = 4;
constexpr int kNW   = kLPAD / kG;   // 4096
constexpr int kS    = kNW / kBS;    // 1024
constexpr int kHD   = kC / kNH;     // 32

constexpr size_t MB        = 1024 * 1024;
constexpr size_t OFF_GIDX   = 0;         // int[LPAD]      1MB
constexpr size_t OFF_WINNER = 1 * MB;    // int[L]         1MB
constexpr size_t OFF_WLIST  = 2 * MB;    // int[L]         1MB
constexpr size_t OFF_CNT    = 3 * MB;    // int[1]
constexpr size_t OFF_X0     = 4 * MB;    // f32[4096*256]  4MB
constexpr size_t OFF_BASE   = 8 * MB;    // f32[4096*256]  4MB
constexpr size_t OFF_ATTN   = 12 * MB;   // bf16[4096*256] 2MB
constexpr size_t OFF_QH     = 16 * MB;   // bf16 2MB
constexpr size_t OFF_KH     = 18 * MB;   // 2MB
constexpr size_t OFF_VH     = 20 * MB;   // 2MB
constexpr size_t OFF_X1     = 24 * MB;   // f32[4096*256]  4MB
constexpr size_t OFF_FF1    = 32 * MB;   // bf16[4096*2048] 16MB
constexpr size_t OFF_WINB   = 64 * MB;                 // bf16[768*256]  384KB
constexpr size_t OFF_WOUTB  = OFF_WINB  + 512 * 1024;  // bf16[256*256]  128KB
constexpr size_t OFF_W1B    = OFF_WOUTB + 256 * 1024;  // bf16[2048*256] 1MB
constexpr size_t OFF_W2B    = OFF_W1B   + 1536 * 1024; // bf16[256*2048] 1MB
constexpr size_t OFF_WP1B   = OFF_W2B   + 1536 * 1024; // bf16[256*256]  128KB
constexpr size_t OFF_WP2B   = OFF_WP1B  + 256 * 1024;  // bf16[256*256]  128KB

typedef __attribute__((ext_vector_type(8))) short bf16x8;
typedef __attribute__((ext_vector_type(4))) float f32x4;

__device__ inline unsigned short f2bf(float f) {
  union { float f; unsigned int u; } x; x.f = f;
  unsigned int r = x.u + 0x7fff + ((x.u >> 16) & 1);   // RNE
  return (unsigned short)(r >> 16);
}
} // namespace

// ---------------------------------------------------------------- winner init (int4 per thread)
__global__ __launch_bounds__(256) void k_initw(int* __restrict__ winner,
                                               int* __restrict__ cnt) {
  int i = blockIdx.x * 256 + threadIdx.x;
  ((int4*)winner)[i] = make_int4(-1, -1, -1, -1);
  if (i == 0) cnt[0] = 0;
}

// ---------------------------------------------------------------- winner (4 per thread)
__global__ __launch_bounds__(256) void k_winner(const int* __restrict__ x_idx,
                                                int* __restrict__ winner) {
  int i0 = (blockIdx.x * 256 + threadIdx.x) * 4;
  int4 xi = *(const int4*)&x_idx[i0];
  atomicMax(&winner[xi.x], i0);
  atomicMax(&winner[xi.y], i0 + 1);
  atomicMax(&winner[xi.z], i0 + 2);
  atomicMax(&winner[xi.w], i0 + 3);
}

// ---------------------------------------------------------------- merged: compact (blk<256, 4/thread) + weight casts
__global__ __launch_bounds__(256) void k_fc(const int* __restrict__ x_idx,
                                            const int* __restrict__ winner,
                                            int* __restrict__ wlist,
                                            int* __restrict__ cnt,
                                            const float* __restrict__ in_proj_w,
                                            const float* __restrict__ out_proj_w,
                                            const float* __restrict__ lin1_w,
                                            const float* __restrict__ lin2_w,
                                            const float* __restrict__ proj_w,
                                            unsigned short* __restrict__ WINB,
                                            unsigned short* __restrict__ WOUTB,
                                            unsigned short* __restrict__ W1B,
                                            unsigned short* __restrict__ W2B,
                                            unsigned short* __restrict__ WP1,
                                            unsigned short* __restrict__ WP2) {
  int blk = blockIdx.x, t = threadIdx.x;
  if (blk < 256) {                      // compact, 4 elements/thread
    int i0 = (blk * 256 + t) * 4;
    int4 xi = *(const int4*)&x_idx[i0];
    #pragma unroll
    for (int j = 0; j < 4; ++j) {
      int i = i0 + j;
      int xv = (j == 0) ? xi.x : (j == 1) ? xi.y : (j == 2) ? xi.z : xi.w;
      if (winner[xv] == i) {
        int p = atomicAdd(cnt, 1);
        wlist[p] = i;
      }
    }
    return;
  }
  int b2 = blk - 256;                   // weight casts
  const float* src = nullptr; unsigned short* dst = nullptr; int i = 0;
  if (b2 < 192)       { src = in_proj_w;  dst = WINB;  i = b2 * 256 + t; }
  else if (b2 < 256)  { src = out_proj_w; dst = WOUTB; i = (b2 - 192) * 256 + t; }
  else if (b2 < 768)  { src = lin1_w;     dst = W1B;   i = (b2 - 256) * 256 + t; }
  else if (b2 < 1280) { src = lin2_w;     dst = W2B;   i = (b2 - 768) * 256 + t; }
  else {
    int c = b2 - 1280;
    WP1[c * kC + t] = f2bf(proj_w[(size_t)c * (2 * kC) + t]);
    WP2[c * kC + t] = f2bf(proj_w[(size_t)c * (2 * kC) + kC + t]);
    return;
  }
  float4 v = ((const float4*)src)[i];
  ushort4 b;
  b.x = f2bf(v.x); b.y = f2bf(v.y); b.z = f2bf(v.z); b.w = f2bf(v.w);
  ((ushort4*)dst)[i] = b;
}

// ---------------------------------------------------------------- merged: pool (blk<4096, wave-per-row) + copy (8 rows/blk)
__global__ __launch_bounds__(256) void k_pc(const float* __restrict__ feats,
                                            const int* __restrict__ x_idx,
                                            const int* __restrict__ flat2win,
                                            const int* __restrict__ winner,
                                            int* __restrict__ gidx,
                                            float* __restrict__ x0,
                                            float* __restrict__ out) {
  int blk = blockIdx.x, t = threadIdx.x;
  int w = t >> 6, lane = t & 63;
  if (blk < kNW) {                       // pool: wave w handles rows w*16..w*16+15
    __shared__ int rows[kG];
    __shared__ __align__(16) float mred[4][kC];
    if (t < kG) {
      int g = x_idx[flat2win[blk * kG + t]];
      rows[t] = g;
      gidx[blk * kG + t] = g;
    }
    __syncthreads();
    float4 mx = make_float4(-INFINITY, -INFINITY, -INFINITY, -INFINITY);
    #pragma unroll
    for (int i = 0; i < 16; ++i) {
      int r = rows[w * 16 + i];
      float4 v = *(const float4*)&feats[(size_t)r * kC + lane * 4];
      mx.x = fmaxf(mx.x, v.x); mx.y = fmaxf(mx.y, v.y);
      mx.z = fmaxf(mx.z, v.z); mx.w = fmaxf(mx.w, v.w);
    }
    *(float4*)&mred[w][lane * 4] = mx;
    __syncthreads();
    x0[blk * kC + t] = fmaxf(fmaxf(mred[0][t], mred[1][t]),
                             fmaxf(mred[2][t], mred[3][t]));
    return;
  }
  // copy rows not overwritten by fuse scatter: 8 rows per block (2 per wave)
  int cb = blk - kNW;                    // 0..32767  (kL/8 blocks)
  #pragma unroll
  for (int i = 0; i < 2; ++i) {
    int row = cb * 8 + w * 2 + i;
    if (winner[row] < 0) {
      *(float4*)&out[(size_t)row * kC + lane * 4] =
          *(const float4*)&feats[(size_t)row * kC + lane * 4];
    }
  }
}

// ================================================================ transformer device bodies
__device__ __forceinline__ void qkv_body(int sec, int my, char* smem,
                                         const float* __restrict__ A,
                                         const unsigned short* __restrict__ Wb,
                                         const float* __restrict__ bias,
                                         unsigned short* __restrict__ Qh,
                                         unsigned short* __restrict__ Kh,
                                         unsigned short* __restrict__ Vh) {
  const float scale = 0.17677669529663687f;   // 1/sqrt(32)
  const int m0 = my * 64;
  const int t = threadIdx.x;
  const int lane = t & 63, w = t >> 6;
  const int c0 = w * 64;
  const int kb = lane >> 4, lr = lane & 15;
  char* As = smem;                             // 32KB swizzled

  f32x4 acc[4][4] = {};
  #pragma unroll
  for (int i = 0; i < 16; ++i) {
    int row = i * 4 + w;
    float4 f4 = *(const float4*)&A[(size_t)(m0 + row) * kC + lane * 4];
    ushort4 b4;
    b4.x = f2bf(f4.x); b4.y = f2bf(f4.y); b4.z = f2bf(f4.z); b4.w = f2bf(f4.w);
    unsigned int off = (((unsigned)row * 512u) + (unsigned)lane * 8u) ^ (((unsigned)row & 7u) << 4);
    *(ushort4*)(As + off) = b4;
  }
  __syncthreads();

  #pragma unroll
  for (int ks = 0; ks < 8; ++ks) {
    const int k0 = ks * 32;
    bf16x8 a[4], b[4];
    #pragma unroll
    for (int rt = 0; rt < 4; ++rt) {
      int row = rt * 16 + lr;
      unsigned int off = (((unsigned)row * 512u) + (unsigned)(k0 + kb * 8) * 2u) ^
                         (((unsigned)row & 7u) << 4);
      a[rt] = *(const bf16x8*)(As + off);
    }
    #pragma unroll
    for (int ct = 0; ct < 4; ++ct) {
      int c = sec * kC + c0 + ct * 16 + lr;
      b[ct] = *(const bf16x8*)&Wb[(size_t)c * kC + k0 + kb * 8];
    }
    #pragma unroll
    for (int rt = 0; rt < 4; ++rt)
      #pragma unroll
      for (int ct = 0; ct < 4; ++ct)
        acc[rt][ct] = __builtin_amdgcn_mfma_f32_16x16x32_bf16(a[rt], b[ct], acc[rt][ct], 0, 0, 0);
  }

  unsigned short* dstbuf = (sec == 0) ? Qh : (sec == 1) ? Kh : Vh;
  #pragma unroll
  for (int rt = 0; rt < 4; ++rt) {
    #pragma unroll
    for (int r = 0; r < 4; ++r) {
      int row = m0 + rt * 16 + kb * 4 + r;
      int bb = row >> 10, s = row & 1023;
      #pragma unroll
      for (int ct = 0; ct < 4; ++ct) {
        int c = c0 + ct * 16 + lr;
        float v = acc[rt][ct][r] + bias[sec * kC + c];
        if (sec == 0) v *= scale;
        int h = c >> 5, d = c & 31;
        dstbuf[(((size_t)(bb * kNH + h) * kS) + s) * kHD + d] = f2bf(v);
      }
    }
  }
}

__device__ __forceinline__ void attn_body(int bxq, int bh, char* smem,
                                          const unsigned short* __restrict__ Qh,
                                          const unsigned short* __restrict__ Kh,
                                          const unsigned short* __restrict__ Vh,
                                          unsigned short* __restrict__ attn_out) {
  const int q0 = bxq * 64;
  const int b = bh >> 3, h = bh & 7;
  const int t = threadIdx.x;
  const int lane = t & 63, w = t >> 6;
  const int kb = lane >> 4, lr = lane & 15;

  unsigned short (*Ks)[40]       = (unsigned short (*)[40])(smem);           // 10240B
  unsigned short (*VTs)[136]     = (unsigned short (*)[136])(smem + 10240);  // 8704B
  unsigned short (*Ps)[16][136]  = (unsigned short (*)[16][136])(smem + 18944); // 17408B

  bf16x8 aq = *(const bf16x8*)(Qh + (((size_t)bh * kS) + q0 + w * 16 + lr) * kHD + kb * 8);

  const unsigned short* kbase = Kh + (size_t)bh * kS * kHD;
  const unsigned short* vbase = Vh + (size_t)bh * kS * kHD;

  float m[4], l[4];
  f32x4 O[2] = {};
  #pragma unroll
  for (int r = 0; r < 4; ++r) { m[r] = -INFINITY; l[r] = 0.f; }

  for (int kt = 0; kt < kS / 128; ++kt) {
    {
      int key = t >> 1, d0 = (t & 1) * 16;
      size_t srow = ((size_t)(kt * 128 + key)) * kHD + d0;
      bf16x8 kv0 = *(const bf16x8*)(kbase + srow);
      bf16x8 kv1 = *(const bf16x8*)(kbase + srow + 8);
      *(bf16x8*)&Ks[key][d0] = kv0;
      *(bf16x8*)&Ks[key][d0 + 8] = kv1;
      bf16x8 vv0 = *(const bf16x8*)(vbase + srow);
      bf16x8 vv1 = *(const bf16x8*)(vbase + srow + 8);
      #pragma unroll
      for (int i = 0; i < 8; ++i) {
        VTs[d0 + i][key] = (unsigned short)vv0[i];
        VTs[d0 + 8 + i][key] = (unsigned short)vv1[i];
      }
    }
    __syncthreads();

    f32x4 S[8] = {};
    #pragma unroll
    for (int ct = 0; ct < 8; ++ct) {
      bf16x8 bk = *(const bf16x8*)&Ks[ct * 16 + lr][kb * 8];
      S[ct] = __builtin_amdgcn_mfma_f32_16x16x32_bf16(aq, bk, S[ct], 0, 0, 0);
    }

    float alpha[4];
    #pragma unroll
    for (int r = 0; r < 4; ++r) {
      float tmax = -INFINITY;
      #pragma unroll
      for (int ct = 0; ct < 8; ++ct) tmax = fmaxf(tmax, S[ct][r]);
      #pragma unroll
      for (int off = 8; off; off >>= 1) tmax = fmaxf(tmax, __shfl_xor(tmax, off, 16));
      float newm = fmaxf(m[r], tmax);
      alpha[r] = __expf(m[r] - newm);
      float ps = 0.f;
      #pragma unroll
      for (int ct = 0; ct < 8; ++ct) {
        float p = __expf(S[ct][r] - newm);
        ps += p;
        Ps[w][kb * 4 + r][ct * 16 + lr] = f2bf(p);
      }
      #pragma unroll
      for (int off = 8; off; off >>= 1) ps += __shfl_xor(ps, off, 16);
      l[r] = l[r] * alpha[r] + ps;
      m[r] = newm;
    }
    #pragma unroll
    for (int r = 0; r < 4; ++r) { O[0][r] *= alpha[r]; O[1][r] *= alpha[r]; }

    #pragma unroll
    for (int ks = 0; ks < 4; ++ks) {
      bf16x8 ap = *(const bf16x8*)&Ps[w][lr][ks * 32 + kb * 8];
      #pragma unroll
      for (int ct = 0; ct < 2; ++ct) {
        bf16x8 bv = *(const bf16x8*)&VTs[ct * 16 + lr][ks * 32 + kb * 8];
        O[ct] = __builtin_amdgcn_mfma_f32_16x16x32_bf16(ap, bv, O[ct], 0, 0, 0);
      }
    }
    __syncthreads();
  }

  #pragma unroll
  for (int ct = 0; ct < 2; ++ct) {
    #pragma unroll
    for (int r = 0; r < 4; ++r) {
      size_t row = (size_t)b * kS + q0 + w * 16 + kb * 4 + r;
      attn_out[row * kC + h * kHD + ct * 16 + lr] = f2bf(O[ct][r] / l[r]);
    }
  }
}

template <bool DO_BASE>
__device__ __forceinline__ void gemm_ln_body(int bx, char* smem,
                                             const unsigned short* __restrict__ A,
                                             int K,
                                             const unsigned short* __restrict__ Wb,
                                             const float* __restrict__ bias,
                                             const float* __restrict__ R,
                                             const float* __restrict__ g,
                                             const float* __restrict__ bb,
                                             float* __restrict__ Out,
                                             const unsigned short* __restrict__ WbB,
                                             const float* __restrict__ biasB) {
  const int m0 = bx * 16;
  const int t = threadIdx.x;
  const int lane = t & 63, w = t >> 6;
  const int c0 = w * 64;
  const int kb = lane >> 4, lr = lane & 15;

  char* As = smem;                         // 8KB
  char* Xs = smem + 8192;                  // 8KB
  float (*red)[16][4] = (float (*)[16][4])(smem + 16384);   // 512B

  f32x4 acc[4] = {};
  for (int kc = 0; kc < K; kc += 256) {
    #pragma unroll
    for (int i = 0; i < 2; ++i) {
      int idx = i * 256 + t;
      int row = idx >> 5, seg = idx & 31;
      bf16x8 v = *(const bf16x8*)&A[(size_t)(m0 + row) * K + kc + seg * 8];
      unsigned int off = (((unsigned)row * 512u) + (unsigned)seg * 16u) ^ (((unsigned)row & 7u) << 4);
      *(bf16x8*)(As + off) = v;
    }
    __syncthreads();

    #pragma unroll
    for (int ks = 0; ks < 8; ++ks) {
      const int k0 = ks * 32;
      unsigned int aoff = (((unsigned)lr * 512u) + (unsigned)(k0 + kb * 8) * 2u) ^
                          (((unsigned)lr & 7u) << 4);
      bf16x8 a = *(const bf16x8*)(As + aoff);
      #pragma unroll
      for (int ct = 0; ct < 4; ++ct) {
        bf16x8 b = *(const bf16x8*)&Wb[(size_t)(c0 + ct * 16 + lr) * K + kc + k0 + kb * 8];
        acc[ct] = __builtin_amdgcn_mfma_f32_16x16x32_bf16(a, b, acc[ct], 0, 0, 0);
      }
    }
    __syncthreads();
  }

  float v[4][4];
  float s[4], sq[4];
  #pragma unroll
  for (int r = 0; r < 4; ++r) { s[r] = 0.f; sq[r] = 0.f; }
  #pragma unroll
  for (int r = 0; r < 4; ++r) {
    int row = m0 + kb * 4 + r;
    #pragma unroll
    for (int ct = 0; ct < 4; ++ct) {
      int c = c0 + ct * 16 + lr;
      float x = acc[ct][r] + bias[c] + R[(size_t)row * kC + c];
      v[r][ct] = x;
      s[r] += x;
      sq[r] += x * x;
    }
  }
  #pragma unroll
  for (int r = 0; r < 4; ++r) {
    #pragma unroll
    for (int off = 8; off; off >>= 1) {
      s[r]  += __shfl_xor(s[r], off, 16);
      sq[r] += __shfl_xor(sq[r], off, 16);
    }
    if (lr == 0) { red[0][kb * 4 + r][w] = s[r]; red[1][kb * 4 + r][w] = sq[r]; }
  }
  __syncthreads();

  #pragma unroll
  for (int r = 0; r < 4; ++r) {
    int lrow = kb * 4 + r;
    float su = red[0][lrow][0] + red[0][lrow][1] + red[0][lrow][2] + red[0][lrow][3];
    float sg = red[1][lrow][0] + red[1][lrow][1] + red[1][lrow][2] + red[1][lrow][3];
    float mu = su * (1.0f / kC);
    float var = sg * (1.0f / kC) - mu * mu;
    float rs = rsqrtf(var + 1e-5f);
    #pragma unroll
    for (int ct = 0; ct < 4; ++ct) {
      int c = c0 + ct * 16 + lr;
      float yv = (v[r][ct] - mu) * rs * g[c] + bb[c];
      if (!DO_BASE) {
        Out[(size_t)(m0 + lrow) * kC + c] = yv;
      } else {
        unsigned int off = (((unsigned)lrow * 512u) + (unsigned)c * 2u) ^ (((unsigned)lrow & 7u) << 4);
        *(unsigned short*)(Xs + off) = f2bf(yv);
      }
    }
  }

  if (DO_BASE) {
    __syncthreads();
    f32x4 acc2[4] = {};
    #pragma unroll
    for (int ks = 0; ks < 8; ++ks) {
      const int k0 = ks * 32;
      unsigned int aoff = (((unsigned)lr * 512u) + (unsigned)(k0 + kb * 8) * 2u) ^
                          (((unsigned)lr & 7u) << 4);
      bf16x8 a = *(const bf16x8*)(Xs + aoff);
      #pragma unroll
      for (int ct = 0; ct < 4; ++ct) {
        bf16x8 b = *(const bf16x8*)&WbB[(size_t)(c0 + ct * 16 + lr) * kC + k0 + kb * 8];
        acc2[ct] = __builtin_amdgcn_mfma_f32_16x16x32_bf16(a, b, acc2[ct], 0, 0, 0);
      }
    }
    #pragma unroll
    for (int r = 0; r < 4; ++r) {
      int row = m0 + kb * 4 + r;
      #pragma unroll
      for (int ct = 0; ct < 4; ++ct) {
        int c = c0 + ct * 16 + lr;
        Out[(size_t)row * kC + c] = acc2[ct][r] + biasB[c];
      }
    }
  }
}

__device__ __forceinline__ void ff1_body(int nx, int my, char* smem,
                                         const float* __restrict__ A,
                                         const unsigned short* __restrict__ Wb,
                                         const float* __restrict__ bias,
                                         unsigned short* __restrict__ Cc) {
  const int m0 = my * 64;
  const int nb = nx * 256;
  const int t = threadIdx.x;
  const int lane = t & 63, w = t >> 6;
  const int c0 = nb + w * 64;
  const int kb = lane >> 4, lr = lane & 15;
  char* As = smem;                        // 32KB

  f32x4 acc[4][4] = {};
  #pragma unroll
  for (int i = 0; i < 16; ++i) {
    int row = i * 4 + w;
    float4 f4 = *(const float4*)&A[(size_t)(m0 + row) * kC + lane * 4];
    ushort4 b4;
    b4.x = f2bf(f4.x); b4.y = f2bf(f4.y); b4.z = f2bf(f4.z); b4.w = f2bf(f4.w);
    unsigned int off = (((unsigned)row * 512u) + (unsigned)lane * 8u) ^ (((unsigned)row & 7u) << 4);
    *(ushort4*)(As + off) = b4;
  }
  __syncthreads();

  #pragma unroll
  for (int ks = 0; ks < 8; ++ks) {
    const int k0 = ks * 32;
    bf16x8 a[4], b[4];
    #pragma unroll
    for (int rt = 0; rt < 4; ++rt) {
      int row = rt * 16 + lr;
      unsigned int off = (((unsigned)row * 512u) + (unsigned)(k0 + kb * 8) * 2u) ^
                         (((unsigned)row & 7u) << 4);
      a[rt] = *(const bf16x8*)(As + off);
    }
    #pragma unroll
    for (int ct = 0; ct < 4; ++ct) {
      int c = c0 + ct * 16 + lr;
      b[ct] = *(const bf16x8*)&Wb[(size_t)c * kC + k0 + kb * 8];
    }
    #pragma unroll
    for (int rt = 0; rt < 4; ++rt)
      #pragma unroll
      for (int ct = 0; ct < 4; ++ct)
        acc[rt][ct] = __builtin_amdgcn_mfma_f32_16x16x32_bf16(a[rt], b[ct], acc[rt][ct], 0, 0, 0);
  }

  #pragma unroll
  for (int rt = 0; rt < 4; ++rt) {
    #pragma unroll
    for (int r = 0; r < 4; ++r) {
      int row = m0 + rt * 16 + kb * 4 + r;
      #pragma unroll
      for (int ct = 0; ct < 4; ++ct) {
        int c = c0 + ct * 16 + lr;
        float vv = fmaxf(acc[rt][ct][r] + bias[c], 0.f);
        Cc[(size_t)row * kFF + c] = f2bf(vv);
      }
    }
  }
}

// ---------------------------------------------------------------- transformer args + standalone kernels
struct FormerArgs {
  const float* x0;
  const unsigned short* WINB; const float* in_proj_b;
  unsigned short* Qh; unsigned short* Kh; unsigned short* Vh;
  unsigned short* attnb;
  const unsigned short* WOUTB; const float* out_proj_b;
  const float* ln1_g; const float* ln1_b; float* x1;
  const unsigned short* W1B; const float* lin1_b; unsigned short* ff1b;
  const unsigned short* W2B; const float* lin2_b;
  const float* ln2_g; const float* ln2_b;
  const unsigned short* WP1B; const float* proj_b; float* basep;
};

__global__ __launch_bounds__(256) void k_qkv_sa(FormerArgs a) {
  __shared__ __align__(16) char smem[32768];
  qkv_body(blockIdx.x, blockIdx.y, smem, a.x0, a.WINB, a.in_proj_b, a.Qh, a.Kh, a.Vh);
}
__global__ __launch_bounds__(256) void k_attn_sa(FormerArgs a) {
  __shared__ __align__(16) char smem[36352];
  attn_body(blockIdx.x, blockIdx.y, smem, a.Qh, a.Kh, a.Vh, a.attnb);
}
__global__ __launch_bounds__(256) void k_ln1_sa(FormerArgs a) {
  __shared__ __align__(16) char smem[16896];
  gemm_ln_body<false>(blockIdx.x, smem, a.attnb, kC, a.WOUTB, a.out_proj_b,
                      a.x0, a.ln1_g, a.ln1_b, a.x1, nullptr, nullptr);
}
__global__ __launch_bounds__(256) void k_ff1_sa(FormerArgs a) {
  __shared__ __align__(16) char smem[32768];
  ff1_body(blockIdx.x, blockIdx.y, smem, a.x1, a.W1B, a.lin1_b, a.ff1b);
}
__global__ __launch_bounds__(256) void k_ln2_sa(FormerArgs a) {
  __shared__ __align__(16) char smem[16896];
  gemm_ln_body<true>(blockIdx.x, smem, a.ff1b, kFF, a.W2B, a.lin2_b,
                     a.x1, a.ln2_g, a.ln2_b, a.basep, a.WP1B, a.proj_b);
}

// ---------------------------------------------------------------- fuse: bf16 MFMA GEMM (gathered A) + scatter
__global__ __launch_bounds__(256) void k_fuse(const float* __restrict__ feats,
                                              const int* __restrict__ gidx,
                                              const int* __restrict__ wlist,
                                              const int* __restrict__ cnt,
                                              const int* __restrict__ win2flat,
                                              const int* __restrict__ x_idx,
                                              const float* __restrict__ base,
                                              const unsigned short* __restrict__ W2B,
                                              float* __restrict__ out) {
  const int count = cnt[0];
  const int r0 = blockIdx.x * 64;
  if (r0 >= count) return;
  const int nr = min(64, count - r0);
  const int t = threadIdx.x;
  const int lane = t & 63, w = t >> 6;

  __shared__ __align__(16) unsigned short As[64 * 256];
  __shared__ int dstrow[64], wwin[64], srcrow[64];

  if (t < 64) {
    int rr = min(r0 + t, count - 1);
    int i = wlist[rr];
    int j = win2flat[i];
    srcrow[t] = gidx[j];
    wwin[t] = j >> 6;
    dstrow[t] = x_idx[i];
  }
  __syncthreads();

  for (int i = 0; i < 16; ++i) {
    int row = i * 4 + w;
    float4 f4 = *(const float4*)&feats[(size_t)srcrow[row] * kC + lane * 4];
    ushort4 b4;
    b4.x = f2bf(f4.x); b4.y = f2bf(f4.y); b4.z = f2bf(f4.z); b4.w = f2bf(f4.w);
    unsigned int off = (((unsigned)row * 512u) + (unsigned)lane * 8u) ^ (((unsigned)row & 7u) << 4);
    *(ushort4*)((char*)As + off) = b4;
  }
  __syncthreads();

  const int c0 = w * 64;
  const int kb = lane >> 4;
  const int lr = lane & 15;
  f32x4 acc[4][4] = {};
  for (int ks = 0; ks < 8; ++ks) {
    const int k0 = ks * 32;
    bf16x8 a[4], b[4];
    #pragma unroll
    for (int rt = 0; rt < 4; ++rt) {
      int row = rt * 16 + lr;
      unsigned int off = (((unsigned)row * 512u) + (unsigned)(k0 + kb * 8) * 2u) ^
                         (((unsigned)row & 7u) << 4);
      a[rt] = *(const bf16x8*)((const char*)As + off);
    }
    #pragma unroll
    for (int ct = 0; ct < 4; ++ct) {
      int c = c0 + ct * 16 + lr;
      b[ct] = *(const bf16x8*)&W2B[(size_t)c * kC + k0 + kb * 8];
    }
    #pragma unroll
    for (int rt = 0; rt < 4; ++rt)
      #pragma unroll
      for (int ct = 0; ct < 4; ++ct)
        acc[rt][ct] = __builtin_amdgcn_mfma_f32_16x16x32_bf16(a[rt], b[ct], acc[rt][ct], 0, 0, 0);
  }

  #pragma unroll
  for (int rt = 0; rt < 4; ++rt) {
    #pragma unroll
    for (int r = 0; r < 4; ++r) {
      int row = rt * 16 + kb * 4 + r;
      if (row < nr) {
        size_t orow = (size_t)dstrow[row] * kC;
        size_t brow = (size_t)wwin[row] * kC;
        #pragma unroll
        for (int ct = 0; ct < 4; ++ct) {
          int c = c0 + ct * 16 + lr;
          out[orow + c] = acc[rt][ct][r] + base[brow + c];
        }
      }
    }
  }
}

// ---------------------------------------------------------------- launch
extern "C" void kernel_launch(void* const* d_in, const int* in_sizes, int n_in,
                              void* d_out, int out_size, void* d_ws, size_t ws_size,
                              hipStream_t stream) {
  const float* feats      = (const float*)d_in[0];
  const int*   x_idx      = (const int*)d_in[1];
  const int*   flat2win   = (const int*)d_in[2];
  const int*   win2flat   = (const int*)d_in[3];
  const float* in_proj_w  = (const float*)d_in[4];
  const float* in_proj_b  = (const float*)d_in[5];
  const float* out_proj_w = (const float*)d_in[6];
  const float* out_proj_b = (const float*)d_in[7];
  const float* lin1_w     = (const float*)d_in[8];
  const float* lin1_b     = (const float*)d_in[9];
  const float* lin2_w     = (const float*)d_in[10];
  const float* lin2_b     = (const float*)d_in[11];
  const float* ln1_g      = (const float*)d_in[12];
  const float* ln1_b      = (const float*)d_in[13];
  const float* ln2_g      = (const float*)d_in[14];
  const float* ln2_b      = (const float*)d_in[15];
  const float* proj_w     = (const float*)d_in[16];
  const float* proj_b     = (const float*)d_in[17];

  char* ws = (char*)d_ws;
  int*   gidx   = (int*)(ws + OFF_GIDX);
  int*   winner = (int*)(ws + OFF_WINNER);
  int*   wlist  = (int*)(ws + OFF_WLIST);
  int*   cnt    = (int*)(ws + OFF_CNT);
  float* x0     = (float*)(ws + OFF_X0);
  float* basep  = (float*)(ws + OFF_BASE);
  float* x1     = (float*)(ws + OFF_X1);
  unsigned short* attnb = (unsigned short*)(ws + OFF_ATTN);
  unsigned short* Qh    = (unsigned short*)(ws + OFF_QH);
  unsigned short* Kh    = (unsigned short*)(ws + OFF_KH);
  unsigned short* Vh    = (unsigned short*)(ws + OFF_VH);
  unsigned short* ff1b  = (unsigned short*)(ws + OFF_FF1);
  unsigned short* WINB  = (unsigned short*)(ws + OFF_WINB);
  unsigned short* WOUTB = (unsigned short*)(ws + OFF_WOUTB);
  unsigned short* W1B   = (unsigned short*)(ws + OFF_W1B);
  unsigned short* W2B   = (unsigned short*)(ws + OFF_W2B);
  unsigned short* WP1B  = (unsigned short*)(ws + OFF_WP1B);
  unsigned short* WP2B  = (unsigned short*)(ws + OFF_WP2B);
  float* out    = (float*)d_out;

  k_initw<<<kL / 1024, 256, 0, stream>>>(winner, cnt);
  k_winner<<<kL / 1024, 256, 0, stream>>>(x_idx, winner);
  k_fc<<<256 + 1536, 256, 0, stream>>>(x_idx, winner, wlist, cnt,
                                       in_proj_w, out_proj_w, lin1_w, lin2_w, proj_w,
                                       WINB, WOUTB, W1B, W2B, WP1B, WP2B);
  k_pc<<<kNW + kL / 8, 256, 0, stream>>>(feats, x_idx, flat2win, winner, gidx, x0, out);

  FormerArgs fa;
  fa.x0 = x0; fa.WINB = WINB; fa.in_proj_b = in_proj_b;
  fa.Qh = Qh; fa.Kh = Kh; fa.Vh = Vh;
  fa.attnb = attnb;
  fa.WOUTB = WOUTB; fa.out_proj_b = out_proj_b;
  fa.ln1_g = ln1_g; fa.ln1_b = ln1_b; fa.x1 = x1;
  fa.W1B = W1B; fa.lin1_b = lin1_b; fa.ff1b = ff1b;
  fa.W2B = W2B; fa.lin2_b = lin2_b;
  fa.ln2_g = ln2_g; fa.ln2_b = ln2_b;
  fa.WP1B = WP1B; fa.proj_b = proj_b; fa.basep = basep;

  k_qkv_sa<<<dim3(3, kNW / 64), 256, 0, stream>>>(fa);
  k_attn_sa<<<dim3(kS / 64, kBS * kNH), 256, 0, stream>>>(fa);
  k_ln1_sa<<<kNW / 16, 256, 0, stream>>>(fa);
  k_ff1_sa<<<dim3(kFF / 256, kNW / 64), 256, 0, stream>>>(fa);
  k_ln2_sa<<<kNW / 16, 256, 0, stream>>>(fa);

  k_fuse<<<kL / 64, 256, 0, stream>>>(feats, gidx, wlist, cnt, win2flat, x_idx,
                                      basep, WP2B, out);
}